// Round 5
// baseline (94.474 us; speedup 1.0000x reference)
//
#include <hip/hip_runtime.h>
#include <cstdint>

typedef unsigned short ushort_t;
typedef __attribute__((ext_vector_type(4))) float f32x4;
typedef __attribute__((ext_vector_type(8))) __bf16 bf16x8;
typedef __attribute__((ext_vector_type(8))) unsigned short ushort8;

#define NB 16384
#define DK 1024   // IN + H

// f32 -> bf16 bits, round-to-nearest-even
__device__ __forceinline__ unsigned short f2b(float f) {
    unsigned u = __builtin_bit_cast(unsigned, f);
    unsigned r = u + 0x7fffu + ((u >> 16) & 1u);
    return (unsigned short)(r >> 16);
}
__device__ __forceinline__ float b2f(ushort_t b) {
    unsigned u = ((unsigned)b) << 16;
    return __builtin_bit_cast(float, u);
}
// fast sigmoid / tanh via v_exp_f32 (+ fast divide); abs err ~1e-6
__device__ __forceinline__ float fast_sigmoid(float x) {
    return __fdividef(1.0f, 1.0f + __expf(-x));
}
__device__ __forceinline__ float fast_tanh(float x) {
    return __fdividef(2.0f, 1.0f + __expf(-2.0f * x)) - 1.0f;
}

// async global->LDS, 16B per lane (LDS dest = wave-uniform base + lane*16)
__device__ __forceinline__ void gll16(const void* g, void* lds) {
    __builtin_amdgcn_global_load_lds(
        (__attribute__((address_space(1))) unsigned int*)(uintptr_t)g,
        (__attribute__((address_space(3))) unsigned int*)(unsigned int)(uintptr_t)lds,
        16, 0, 0);
}

// ---------------- prep kernels ----------------

__global__ __launch_bounds__(256) void k_f32_to_bf16(const float* __restrict__ s,
                                                     ushort_t* __restrict__ d) {
    size_t g = (size_t)blockIdx.x * 256 + threadIdx.x;
    const float* p = s + g * 8;
    f32x4 f0 = *(const f32x4*)p;
    f32x4 f1 = *(const f32x4*)(p + 4);
    ushort8 o;
#pragma unroll
    for (int j = 0; j < 4; ++j) { o[j] = f2b(f0[j]); o[j + 4] = f2b(f1[j]); }
    *(ushort8*)(d + g * 8) = o;
}

// W [1024][ncols] f32 ([k][n]) -> Wt [ncols][1024] bf16 ([n][k])
__global__ __launch_bounds__(256) void k_transpose_w(const float* __restrict__ W,
                                                     ushort_t* __restrict__ Wt, int ncols) {
    __shared__ float tile[32][33];
    int n0 = blockIdx.x * 32, k0 = blockIdx.y * 32;
    int tx = threadIdx.x, ty = threadIdx.y;  // blockDim (32,8)
#pragma unroll
    for (int i = 0; i < 32; i += 8)
        tile[ty + i][tx] = W[(size_t)(k0 + ty + i) * ncols + n0 + tx];
    __syncthreads();
#pragma unroll
    for (int i = 0; i < 32; i += 8)
        Wt[(size_t)(n0 + ty + i) * DK + k0 + tx] = f2b(tile[tx][ty + i]);
}

// ---------------- GEMM 1: lin = [x,h] @ W_in, fused gate epilogue ----------------
// Tri-buffered pipeline, counted vmcnt (T4), raw s_barrier, setprio (T5).
// Loads for tile t+2 issued at iter t -> ~2 compute phases in flight (covers HBM lat).
__global__ __launch_bounds__(256, 2) void k_gemm1(
    const ushort_t* __restrict__ XB, const ushort_t* __restrict__ HB,
    const ushort_t* __restrict__ WT, const float* __restrict__ b_in,
    float* __restrict__ hnew, ushort_t* __restrict__ HN) {
    __shared__ ushort_t As[3][128 * 32];
    __shared__ ushort_t BsL[3][128 * 32];
    __shared__ ushort_t BsF[3][128 * 32];

    const int t = threadIdx.x;
    const int lane = t & 63;
    const int wave = t >> 6;
    const int wm = wave >> 1, wn = wave & 1;  // 2x2 waves over 128x128
    const int m0 = blockIdx.x * 128;
    const int n0 = blockIdx.y * 128;  // in [0,512)

    f32x4 accL[4][4] = {};
    f32x4 accF[4][4] = {};

    const int srow = t >> 2;        // staging row 0..63
    const int skel = (t & 3) * 8;   // staging k-elem offset
    const size_t arow = (size_t)(m0 + srow) * 512;
    const ushort_t* gBL = WT + (size_t)(n0 + srow) * DK + skel;
    const ushort_t* gBF = WT + (size_t)(n0 + 512 + srow) * DK + skel;

    auto stage = [&](int it, int buf) {   // 6 gll16 per tile
        const int kt = it * 32;
        const ushort_t* abase =
            (kt < 512) ? (XB + arow + kt + skel) : (HB + arow + (kt - 512) + skel);
        ushort_t* a  = &As[buf][t * 8];
        ushort_t* bl = &BsL[buf][t * 8];
        ushort_t* bf = &BsF[buf][t * 8];
        gll16(abase, a);
        gll16(abase + 64 * 512, a + 64 * 32);
        gll16(gBL + kt, bl);
        gll16(gBL + kt + 64 * DK, bl + 64 * 32);
        gll16(gBF + kt, bf);
        gll16(gBF + kt + 64 * DK, bf + 64 * 32);
    };

    const int fr = lane & 15;
    const int kq = (lane >> 4) * 8;

    stage(0, 0);
    stage(1, 1);
    int cur = 0;
    for (int it = 0; it < 32; ++it) {
        // counted wait: tile it's 6 loads are the oldest; tile it+1's 6 stay in flight.
        // Tail (it==31): no younger loads exist -> must drain to 0.
        if (it < 31) asm volatile("s_waitcnt vmcnt(6)" ::: "memory");
        else         asm volatile("s_waitcnt vmcnt(0)" ::: "memory");
        __builtin_amdgcn_s_barrier();     // raw: no compiler-injected vmcnt(0) drain
        asm volatile("" ::: "memory");
        __builtin_amdgcn_sched_barrier(0);

        int wbuf = cur - 1; if (wbuf < 0) wbuf = 2;   // (cur+2)%3
        if (it < 30) stage(it + 2, wbuf);             // issue-early, lands over 2 iters

        bf16x8 av[4], blv[4], bfv[4];
#pragma unroll
        for (int i = 0; i < 4; ++i) {
            av[i]  = *(const bf16x8*)(&As[cur][(wm * 64 + i * 16 + fr) * 32 + kq]);
            blv[i] = *(const bf16x8*)(&BsL[cur][(wn * 64 + i * 16 + fr) * 32 + kq]);
            bfv[i] = *(const bf16x8*)(&BsF[cur][(wn * 64 + i * 16 + fr) * 32 + kq]);
        }
        __builtin_amdgcn_s_setprio(1);
#pragma unroll
        for (int i = 0; i < 4; ++i)
#pragma unroll
            for (int j = 0; j < 4; ++j) {
                accL[i][j] = __builtin_amdgcn_mfma_f32_16x16x32_bf16(av[i], blv[j], accL[i][j], 0, 0, 0);
                accF[i][j] = __builtin_amdgcn_mfma_f32_16x16x32_bf16(av[i], bfv[j], accF[i][j], 0, 0, 0);
            }
        __builtin_amdgcn_s_setprio(0);
        cur = (cur == 2) ? 0 : cur + 1;
    }

    // epilogue: C/D map col=lane&15, row=(lane>>4)*4+reg
    const int fq = lane >> 4;
    float bl4[4], bf4[4];
#pragma unroll
    for (int j = 0; j < 4; ++j) {
        const int c = n0 + wn * 64 + j * 16 + fr;
        bl4[j] = b_in[c];
        bf4[j] = b_in[c + 512];
    }
#pragma unroll
    for (int i = 0; i < 4; ++i)
#pragma unroll
        for (int j = 0; j < 4; ++j) {
            const int c = n0 + wn * 64 + j * 16 + fr;
#pragma unroll
            for (int r = 0; r < 4; ++r) {
                const int row = m0 + wm * 64 + i * 16 + fq * 4 + r;
                float lp = accL[i][j][r] + bl4[j];
                float fp = accF[i][j][r] + bf4[j];
                float hv = b2f(HB[(size_t)row * 512 + c]);
                float fm = fast_sigmoid(fp);
                float lr = fast_tanh(lp);
                float hn = fm * hv + (1.0f - fm) * lr;
                hnew[(size_t)row * 512 + c] = hn;
                HN[(size_t)row * 512 + c] = f2b(hn);
            }
        }
}

// ---------------- GEMM 2: out = tanh([x,h_new] @ W_out + b_out) ----------------
__global__ __launch_bounds__(256, 3) void k_gemm2(
    const ushort_t* __restrict__ XB, const ushort_t* __restrict__ HN,
    const ushort_t* __restrict__ WT, const float* __restrict__ b_out,
    float* __restrict__ out) {
    __shared__ ushort_t As[3][128 * 32];
    __shared__ ushort_t Bs[3][128 * 32];

    const int t = threadIdx.x;
    const int lane = t & 63;
    const int wave = t >> 6;
    const int wm = wave >> 1, wn = wave & 1;
    const int m0 = blockIdx.x * 128;
    const int n0 = blockIdx.y * 128;

    f32x4 acc[4][4] = {};

    const int srow = t >> 2;
    const int skel = (t & 3) * 8;
    const size_t arow = (size_t)(m0 + srow) * 512;
    const ushort_t* gB = WT + (size_t)(n0 + srow) * DK + skel;

    auto stage = [&](int it, int buf) {   // 4 gll16 per tile
        const int kt = it * 32;
        const ushort_t* abase =
            (kt < 512) ? (XB + arow + kt + skel) : (HN + arow + (kt - 512) + skel);
        ushort_t* a = &As[buf][t * 8];
        ushort_t* b = &Bs[buf][t * 8];
        gll16(abase, a);
        gll16(abase + 64 * 512, a + 64 * 32);
        gll16(gB + kt, b);
        gll16(gB + kt + 64 * DK, b + 64 * 32);
    };

    const int fr = lane & 15;
    const int kq = (lane >> 4) * 8;

    stage(0, 0);
    stage(1, 1);
    int cur = 0;
    for (int it = 0; it < 32; ++it) {
        if (it < 31) asm volatile("s_waitcnt vmcnt(4)" ::: "memory");
        else         asm volatile("s_waitcnt vmcnt(0)" ::: "memory");
        __builtin_amdgcn_s_barrier();
        asm volatile("" ::: "memory");
        __builtin_amdgcn_sched_barrier(0);

        int wbuf = cur - 1; if (wbuf < 0) wbuf = 2;
        if (it < 30) stage(it + 2, wbuf);

        bf16x8 av[4], bv[4];
#pragma unroll
        for (int i = 0; i < 4; ++i) {
            av[i] = *(const bf16x8*)(&As[cur][(wm * 64 + i * 16 + fr) * 32 + kq]);
            bv[i] = *(const bf16x8*)(&Bs[cur][(wn * 64 + i * 16 + fr) * 32 + kq]);
        }
        __builtin_amdgcn_s_setprio(1);
#pragma unroll
        for (int i = 0; i < 4; ++i)
#pragma unroll
            for (int j = 0; j < 4; ++j)
                acc[i][j] = __builtin_amdgcn_mfma_f32_16x16x32_bf16(av[i], bv[j], acc[i][j], 0, 0, 0);
        __builtin_amdgcn_s_setprio(0);
        cur = (cur == 2) ? 0 : cur + 1;
    }

    const int fq = lane >> 4;
#pragma unroll
    for (int i = 0; i < 4; ++i)
#pragma unroll
        for (int j = 0; j < 4; ++j) {
            const int c = n0 + wn * 64 + j * 16 + fr;
#pragma unroll
            for (int r = 0; r < 4; ++r) {
                const int row = m0 + wm * 64 + i * 16 + fq * 4 + r;
                out[(size_t)row * 512 + c] = fast_tanh(acc[i][j][r] + b_out[c]);
            }
        }
}

extern "C" void kernel_launch(void* const* d_in, const int* in_sizes, int n_in,
                              void* d_out, int out_size, void* d_ws, size_t ws_size,
                              hipStream_t stream) {
    const float* x = (const float*)d_in[0];
    const float* h = (const float*)d_in[1];
    const float* W_in = (const float*)d_in[2];
    const float* b_in = (const float*)d_in[3];
    const float* W_out = (const float*)d_in[4];
    const float* b_out = (const float*)d_in[5];

    float* out = (float*)d_out;                    // [16384][512]
    float* hnew = out + (size_t)NB * 512;          // [16384][512]

    ushort_t* XB = (ushort_t*)d_ws;
    ushort_t* HB = XB + (size_t)NB * 512;
    ushort_t* HN = HB + (size_t)NB * 512;
    ushort_t* WTI = HN + (size_t)NB * 512;
    ushort_t* WTO = WTI + (size_t)1024 * 1024;

    k_f32_to_bf16<<<4096, 256, 0, stream>>>(x, XB);
    k_f32_to_bf16<<<4096, 256, 0, stream>>>(h, HB);
    k_transpose_w<<<dim3(32, 32), dim3(32, 8), 0, stream>>>(W_in, WTI, 1024);
    k_transpose_w<<<dim3(16, 32), dim3(32, 8), 0, stream>>>(W_out, WTO, 512);
    k_gemm1<<<dim3(128, 4), 256, 0, stream>>>(XB, HB, WTI, b_in, hnew, HN);
    k_gemm2<<<dim3(128, 4), 256, 0, stream>>>(XB, HN, WTO, b_out, out);
}

// Round 6
// 86.603 us; speedup vs baseline: 1.0909x; 1.0909x over previous
//
#include <hip/hip_runtime.h>
#include <cstdint>

typedef unsigned short ushort_t;
typedef __attribute__((ext_vector_type(4))) float f32x4;
typedef __attribute__((ext_vector_type(8))) __bf16 bf16x8;
typedef __attribute__((ext_vector_type(8))) unsigned short ushort8;

#define NB 16384
#define DK 1024   // IN + H

#define MFMA16(a, b, c) __builtin_amdgcn_mfma_f32_16x16x32_bf16(a, b, c, 0, 0, 0)

// f32 -> bf16 bits, round-to-nearest-even
__device__ __forceinline__ unsigned short f2b(float f) {
    unsigned u = __builtin_bit_cast(unsigned, f);
    unsigned r = u + 0x7fffu + ((u >> 16) & 1u);
    return (unsigned short)(r >> 16);
}
__device__ __forceinline__ float b2f(ushort_t b) {
    unsigned u = ((unsigned)b) << 16;
    return __builtin_bit_cast(float, u);
}
__device__ __forceinline__ float fast_sigmoid(float x) {
    return __fdividef(1.0f, 1.0f + __expf(-x));
}
__device__ __forceinline__ float fast_tanh(float x) {
    return __fdividef(2.0f, 1.0f + __expf(-2.0f * x)) - 1.0f;
}

// async global->LDS, 16B per lane (LDS dest = wave-uniform base + lane*16)
__device__ __forceinline__ void gll16(const void* g, void* lds) {
    __builtin_amdgcn_global_load_lds(
        (__attribute__((address_space(1))) unsigned int*)(uintptr_t)g,
        (__attribute__((address_space(3))) unsigned int*)(unsigned int)(uintptr_t)lds,
        16, 0, 0);
}

// ---------------- prep kernels ----------------
// All staging sources (XB, HB, HN, WT*) are stored PRE-SWIZZLED: within each
// 64-elem K-group of a row, elem index c is stored at c ^ ((row&7)<<3).
// global_load_lds copies linearly -> LDS holds the swizzle -> ds_read applies
// the same XOR. 16B chunks land 8-per-bank-quad: conflict-free b128 reads.

__global__ __launch_bounds__(256) void k_cvt(const float* __restrict__ x,
                                             const float* __restrict__ h,
                                             ushort_t* __restrict__ XB,
                                             ushort_t* __restrict__ HB) {
    int b = blockIdx.x;
    const float* s;
    ushort_t* d;
    if (b < 4096) { s = x; d = XB; } else { s = h; d = HB; b -= 4096; }
    size_t g = (size_t)b * 256 + threadIdx.x;
    const float* p = s + g * 8;
    f32x4 f0 = *(const f32x4*)p;
    f32x4 f1 = *(const f32x4*)(p + 4);
    ushort8 o;
#pragma unroll
    for (int j = 0; j < 4; ++j) { o[j] = f2b(f0[j]); o[j + 4] = f2b(f1[j]); }
    size_t fi = g * 8;
    int row = (int)(fi >> 9);
    int c = (int)(fi & 511);  // multiple of 8
    int swc = (c & ~63) | ((c & 63) ^ ((row & 7) << 3));
    *(ushort8*)(d + (size_t)row * 512 + swc) = o;
}

// W [1024][ncols] f32 ([k][n]) -> Wt [ncols][1024] bf16 ([n][k]), swizzled
__global__ __launch_bounds__(256) void k_transpose_w(const float* __restrict__ W,
                                                     ushort_t* __restrict__ Wt, int ncols) {
    __shared__ float tile[32][33];
    int n0 = blockIdx.x * 32, k0 = blockIdx.y * 32;
    int tx = threadIdx.x, ty = threadIdx.y;  // blockDim (32,8)
#pragma unroll
    for (int i = 0; i < 32; i += 8)
        tile[ty + i][tx] = W[(size_t)(k0 + ty + i) * ncols + n0 + tx];
    __syncthreads();
#pragma unroll
    for (int i = 0; i < 32; i += 8) {
        int n = n0 + ty + i;
        int k = k0 + tx;
        int kk = (k & ~63) | ((k & 63) ^ ((n & 7) << 3));
        Wt[(size_t)n * DK + kk] = f2b(tile[tx][ty + i]);
    }
}

// ---------------- GEMM 1: paired learn/forget, fused gate epilogue ----------------
// BM=256 rows, 128 paired cols (B-LDS: 128 learn rows + 128 forget rows), BK=64.
// 512 threads = 8 waves (2m x 4n). Wave tile: 128 rows x 32 paired cols.
// 4 phases/K-tile: p0 kk0-learn, p1 kk0-forget, p2 kk1-learn, p3 kk1-forget.
// Staging slots: p0: A(i+1,h1)  p1: B(i+1,L)  p2: B(i+1,F)  p3: A(i+2,h0).
// One counted vmcnt(4) per K-tile at p0; 1 barrier per phase.
__global__ __launch_bounds__(512, 1) void k_gemm1(
    const ushort_t* __restrict__ XB, const ushort_t* __restrict__ HB,
    const ushort_t* __restrict__ WT, const float* __restrict__ b_in,
    float* __restrict__ hnew, ushort_t* __restrict__ HN) {
    __shared__ ushort_t As[2][2][128 * 64];  // [dbuf][row-half][128][64]  64KB
    __shared__ ushort_t Bs[2][2][128 * 64];  // [dbuf][L/F][128][64]       64KB

    const int t = threadIdx.x;
    const int lane = t & 63;
    const int wid = t >> 6;
    const int wm = wid >> 2, wn = wid & 3;
    const int m0 = blockIdx.x * 256;
    const int n0 = blockIdx.y * 128;  // paired col base, in [0,512)

    const int srow = t >> 3;          // staging row 0..63
    const int schk = (t & 7) * 8;     // staging elem offset in 64-group

    const int fr = lane & 15, fq = lane >> 4;
    const int xr = (lane & 7) << 3;   // elem XOR (matches source pre-swizzle)

    f32x4 accL[8][2] = {};
    f32x4 accF[8][2] = {};

#define G1_STAGE_A(tile, half) do { \
        int kt_ = (tile) * 64; \
        const ushort_t* s_ = (kt_ < 512) \
            ? (XB + (size_t)(m0 + (half) * 128 + srow) * 512 + kt_ + schk) \
            : (HB + (size_t)(m0 + (half) * 128 + srow) * 512 + (kt_ - 512) + schk); \
        ushort_t* d_ = &As[(tile) & 1][half][t * 8]; \
        gll16(s_, d_); \
        gll16(s_ + 64 * 512, d_ + 64 * 64); \
    } while (0)

#define G1_STAGE_B(tile, half) do { \
        int kt_ = (tile) * 64; \
        const ushort_t* s_ = WT + (size_t)((half) * 512 + n0 + srow) * DK + kt_ + schk; \
        ushort_t* d_ = &Bs[(tile) & 1][half][t * 8]; \
        gll16(s_, d_); \
        gll16(s_ + 64 * DK, d_ + 64 * 64); \
    } while (0)

#define G1_LDA(cb, r, kk) (*(const bf16x8*)&As[cb][wm][((r) * 16 + fr) * 64 + (((kk) * 32 + fq * 8) ^ xr)])
#define G1_LDB(cb, half, j, kk) (*(const bf16x8*)&Bs[cb][half][(wn * 32 + (j) * 16 + fr) * 64 + (((kk) * 32 + fq * 8) ^ xr)])

    // prologue: tile0 fully + tile1 A-h0
    G1_STAGE_A(0, 0); G1_STAGE_A(0, 1); G1_STAGE_B(0, 0); G1_STAGE_B(0, 1);
    G1_STAGE_A(1, 0);

    bf16x8 a[8], b0, b1;
    for (int i = 0; i < 16; ++i) {
        const int cb = i & 1;
        // ---- phase 0: kk0, learn ----
        if (i < 15) G1_STAGE_A(i + 1, 1);
        if (i < 15) asm volatile("s_waitcnt vmcnt(4)" ::: "memory");
        else        asm volatile("s_waitcnt vmcnt(0)" ::: "memory");
        asm volatile("s_barrier" ::: "memory");
#pragma unroll
        for (int r = 0; r < 8; ++r) a[r] = G1_LDA(cb, r, 0);
        b0 = G1_LDB(cb, 0, 0, 0); b1 = G1_LDB(cb, 0, 1, 0);
        __builtin_amdgcn_s_setprio(1);
#pragma unroll
        for (int r = 0; r < 8; ++r) {
            accL[r][0] = MFMA16(a[r], b0, accL[r][0]);
            accL[r][1] = MFMA16(a[r], b1, accL[r][1]);
        }
        __builtin_amdgcn_s_setprio(0);
        // ---- phase 1: kk0, forget ----
        asm volatile("s_barrier" ::: "memory");
        if (i < 15) G1_STAGE_B(i + 1, 0);
        b0 = G1_LDB(cb, 1, 0, 0); b1 = G1_LDB(cb, 1, 1, 0);
        __builtin_amdgcn_s_setprio(1);
#pragma unroll
        for (int r = 0; r < 8; ++r) {
            accF[r][0] = MFMA16(a[r], b0, accF[r][0]);
            accF[r][1] = MFMA16(a[r], b1, accF[r][1]);
        }
        __builtin_amdgcn_s_setprio(0);
        // ---- phase 2: kk1, learn ----
        asm volatile("s_barrier" ::: "memory");
        if (i < 15) G1_STAGE_B(i + 1, 1);
#pragma unroll
        for (int r = 0; r < 8; ++r) a[r] = G1_LDA(cb, r, 1);
        b0 = G1_LDB(cb, 0, 0, 1); b1 = G1_LDB(cb, 0, 1, 1);
        __builtin_amdgcn_s_setprio(1);
#pragma unroll
        for (int r = 0; r < 8; ++r) {
            accL[r][0] = MFMA16(a[r], b0, accL[r][0]);
            accL[r][1] = MFMA16(a[r], b1, accL[r][1]);
        }
        __builtin_amdgcn_s_setprio(0);
        // ---- phase 3: kk1, forget ----
        asm volatile("s_barrier" ::: "memory");
        if (i < 14) G1_STAGE_A(i + 2, 0);
        b0 = G1_LDB(cb, 1, 0, 1); b1 = G1_LDB(cb, 1, 1, 1);
        __builtin_amdgcn_s_setprio(1);
#pragma unroll
        for (int r = 0; r < 8; ++r) {
            accF[r][0] = MFMA16(a[r], b0, accF[r][0]);
            accF[r][1] = MFMA16(a[r], b1, accF[r][1]);
        }
        __builtin_amdgcn_s_setprio(0);
    }

    // epilogue: C/D map col=lane&15, row=(lane>>4)*4+reg ; gate is wave-local
    float blv[2], bfv[2];
#pragma unroll
    for (int j = 0; j < 2; ++j) {
        const int c = n0 + wn * 32 + j * 16 + fr;
        blv[j] = b_in[c];
        bfv[j] = b_in[c + 512];
    }
#pragma unroll
    for (int r = 0; r < 8; ++r)
#pragma unroll
        for (int j = 0; j < 2; ++j) {
            const int c = n0 + wn * 32 + j * 16 + fr;
#pragma unroll
            for (int rr = 0; rr < 4; ++rr) {
                const int row = m0 + wm * 128 + r * 16 + fq * 4 + rr;
                const int swc = (c & ~63) | ((c & 63) ^ ((row & 7) << 3));
                float lp = accL[r][j][rr] + blv[j];
                float fp = accF[r][j][rr] + bfv[j];
                float hv = b2f(HB[(size_t)row * 512 + swc]);
                float fm = fast_sigmoid(fp);
                float lr = fast_tanh(lp);
                float hn = fm * hv + (1.0f - fm) * lr;
                hnew[(size_t)row * 512 + c] = hn;
                HN[(size_t)row * 512 + swc] = f2b(hn);
            }
        }
}

// ---------------- GEMM 2: out = tanh([x,h_new] @ W_out + b_out) ----------------
// BM=256, BN=128, BK=64; 8 waves; wave tile 128 x 32. 4 phases of 8 MFMA.
__global__ __launch_bounds__(512, 1) void k_gemm2(
    const ushort_t* __restrict__ XB, const ushort_t* __restrict__ HN,
    const ushort_t* __restrict__ WT, const float* __restrict__ b_out,
    float* __restrict__ out) {
    __shared__ ushort_t As[2][2][128 * 64];  // 64KB
    __shared__ ushort_t Bs[2][128 * 64];     // 32KB

    const int t = threadIdx.x;
    const int lane = t & 63;
    const int wid = t >> 6;
    const int wm = wid >> 2, wn = wid & 3;
    const int m0 = blockIdx.x * 256;
    const int n0 = blockIdx.y * 128;

    const int srow = t >> 3;
    const int schk = (t & 7) * 8;
    const int fr = lane & 15, fq = lane >> 4;
    const int xr = (lane & 7) << 3;

    f32x4 acc[8][2] = {};

#define G2_STAGE_A(tile, half) do { \
        int kt_ = (tile) * 64; \
        const ushort_t* s_ = (kt_ < 512) \
            ? (XB + (size_t)(m0 + (half) * 128 + srow) * 512 + kt_ + schk) \
            : (HN + (size_t)(m0 + (half) * 128 + srow) * 512 + (kt_ - 512) + schk); \
        ushort_t* d_ = &As[(tile) & 1][half][t * 8]; \
        gll16(s_, d_); \
        gll16(s_ + 64 * 512, d_ + 64 * 64); \
    } while (0)

#define G2_STAGE_Bq(tile, q) do { \
        int kt_ = (tile) * 64; \
        const ushort_t* s_ = WT + (size_t)(n0 + (q) * 64 + srow) * DK + kt_ + schk; \
        ushort_t* d_ = &Bs[(tile) & 1][(q) * 64 * 64 + t * 8]; \
        gll16(s_, d_); \
    } while (0)

#define G2_LDA(cb, r, kk) (*(const bf16x8*)&As[cb][wm][((r) * 16 + fr) * 64 + (((kk) * 32 + fq * 8) ^ xr)])
#define G2_LDB(cb, j, kk) (*(const bf16x8*)&Bs[cb][(wn * 32 + (j) * 16 + fr) * 64 + (((kk) * 32 + fq * 8) ^ xr)])

    G2_STAGE_A(0, 0); G2_STAGE_A(0, 1); G2_STAGE_Bq(0, 0); G2_STAGE_Bq(0, 1);
    G2_STAGE_A(1, 0);

    bf16x8 a[8], b0, b1;
    for (int i = 0; i < 16; ++i) {
        const int cb = i & 1;
        // ---- phase 0: kk0, j0 ----
        if (i < 15) G2_STAGE_A(i + 1, 1);
        if (i < 15) asm volatile("s_waitcnt vmcnt(4)" ::: "memory");
        else        asm volatile("s_waitcnt vmcnt(0)" ::: "memory");
        asm volatile("s_barrier" ::: "memory");
#pragma unroll
        for (int r = 0; r < 8; ++r) a[r] = G2_LDA(cb, r, 0);
        b0 = G2_LDB(cb, 0, 0);
        __builtin_amdgcn_s_setprio(1);
#pragma unroll
        for (int r = 0; r < 8; ++r) acc[r][0] = MFMA16(a[r], b0, acc[r][0]);
        __builtin_amdgcn_s_setprio(0);
        // ---- phase 1: kk0, j1 ----
        asm volatile("s_barrier" ::: "memory");
        if (i < 15) G2_STAGE_Bq(i + 1, 0);
        b1 = G2_LDB(cb, 1, 0);
        __builtin_amdgcn_s_setprio(1);
#pragma unroll
        for (int r = 0; r < 8; ++r) acc[r][1] = MFMA16(a[r], b1, acc[r][1]);
        __builtin_amdgcn_s_setprio(0);
        // ---- phase 2: kk1, j0 ----
        asm volatile("s_barrier" ::: "memory");
        if (i < 15) G2_STAGE_Bq(i + 1, 1);
#pragma unroll
        for (int r = 0; r < 8; ++r) a[r] = G2_LDA(cb, r, 1);
        b0 = G2_LDB(cb, 0, 1);
        __builtin_amdgcn_s_setprio(1);
#pragma unroll
        for (int r = 0; r < 8; ++r) acc[r][0] = MFMA16(a[r], b0, acc[r][0]);
        __builtin_amdgcn_s_setprio(0);
        // ---- phase 3: kk1, j1 ----
        asm volatile("s_barrier" ::: "memory");
        if (i < 14) G2_STAGE_A(i + 2, 0);
        b1 = G2_LDB(cb, 1, 1);
        __builtin_amdgcn_s_setprio(1);
#pragma unroll
        for (int r = 0; r < 8; ++r) acc[r][1] = MFMA16(a[r], b1, acc[r][1]);
        __builtin_amdgcn_s_setprio(0);
    }

#pragma unroll
    for (int r = 0; r < 8; ++r)
#pragma unroll
        for (int j = 0; j < 2; ++j) {
            const int c = n0 + wn * 32 + j * 16 + fr;
            const float bo = b_out[c];
#pragma unroll
            for (int rr = 0; rr < 4; ++rr) {
                const int row = m0 + wm * 128 + r * 16 + fq * 4 + rr;
                out[(size_t)row * 512 + c] = fast_tanh(acc[r][j][rr] + bo);
            }
        }
}

extern "C" void kernel_launch(void* const* d_in, const int* in_sizes, int n_in,
                              void* d_out, int out_size, void* d_ws, size_t ws_size,
                              hipStream_t stream) {
    const float* x = (const float*)d_in[0];
    const float* h = (const float*)d_in[1];
    const float* W_in = (const float*)d_in[2];
    const float* b_in = (const float*)d_in[3];
    const float* W_out = (const float*)d_in[4];
    const float* b_out = (const float*)d_in[5];

    float* out = (float*)d_out;                    // [16384][512]
    float* hnew = out + (size_t)NB * 512;          // [16384][512]

    ushort_t* XB = (ushort_t*)d_ws;
    ushort_t* HB = XB + (size_t)NB * 512;
    ushort_t* HN = HB + (size_t)NB * 512;
    ushort_t* WTI = HN + (size_t)NB * 512;
    ushort_t* WTO = WTI + (size_t)1024 * 1024;

    k_cvt<<<8192, 256, 0, stream>>>(x, h, XB, HB);
    k_transpose_w<<<dim3(32, 32), dim3(32, 8), 0, stream>>>(W_in, WTI, 1024);
    k_transpose_w<<<dim3(16, 32), dim3(32, 8), 0, stream>>>(W_out, WTO, 512);
    k_gemm1<<<dim3(64, 4), 512, 0, stream>>>(XB, HB, WTI, b_in, hnew, HN);
    k_gemm2<<<dim3(64, 4), 512, 0, stream>>>(XB, HN, WTO, b_out, out);
}